// Round 1
// baseline (301.639 us; speedup 1.0000x reference)
//
#include <hip/hip_runtime.h>
#include <math.h>

// Problem constants
#define B_ 32
#define N_ 256
#define D_ 256
#define H_ 8
#define K_ 16

__device__ __constant__ float LOG_EPS_C = -18.420680743952367f;   // ln(1e-8)
#define LOG_INV_K (-2.772588722239781f)                           // ln(1/16)

// ---------------------------------------------------------------------------
// Kernel 1: fuse W_slot @ W_fusion -> W_eff [K,512], b_eff [K]
// ---------------------------------------------------------------------------
__global__ void k_weff(const float* __restrict__ W_fusion,  // [D, 2D] = [256,512]
                       const float* __restrict__ b_fusion,  // [256]
                       const float* __restrict__ W_slot,    // [K, D] = [16,256]
                       const float* __restrict__ b_slot,    // [16]
                       float* __restrict__ W_eff,           // [16,512]
                       float* __restrict__ b_eff) {         // [16]
    int idx = blockIdx.x * 256 + threadIdx.x;   // 0..8191
    int k = idx >> 9, j = idx & 511;
    float s = 0.f;
    #pragma unroll 4
    for (int d = 0; d < 256; ++d)
        s += W_slot[k * 256 + d] * W_fusion[d * 512 + j];
    W_eff[idx] = s;
    if (idx < 16) {
        float t = b_slot[idx];
        for (int d = 0; d < 256; ++d) t += W_slot[idx * 256 + d] * b_fusion[d];
        b_eff[idx] = t;
    }
}

// ---------------------------------------------------------------------------
// Kernel 2: G processing (softmax rows, sinkhorn x10, zero diag) + Frobenius reg
// One block, 256 threads.  G_param [H,K,K] = 2048 elements.
// ---------------------------------------------------------------------------
__global__ void k_G(const float* __restrict__ G_param,
                    float* __restrict__ G_out,     // [H,K,K]
                    float* __restrict__ g_reg) {   // [1]
    __shared__ float M[2048];       // [h][k][l]
    __shared__ float red[256];
    __shared__ float inv_nrm[8];
    __shared__ float hsq[8];        // |v_h|^2 after normalization
    __shared__ float trace_s;
    int t = threadIdx.x;

    // row softmax (G_TEMP = 1.0) then clamp at 1e-6
    if (t < 128) {
        int base = t * 16;
        float v[16];
        float mx = -1e30f;
        #pragma unroll
        for (int l = 0; l < 16; ++l) { v[l] = G_param[base + l]; mx = fmaxf(mx, v[l]); }
        float s = 0.f;
        #pragma unroll
        for (int l = 0; l < 16; ++l) { v[l] = expf(v[l] - mx); s += v[l]; }
        float r = 1.f / s;
        #pragma unroll
        for (int l = 0; l < 16; ++l) M[base + l] = fmaxf(v[l] * r, 1e-6f);
    }
    __syncthreads();

    // sinkhorn, 10 iters: row-normalize then col-normalize, eps=1e-6 on sums
    for (int it = 0; it < 10; ++it) {
        if (t < 128) {   // row (h,k) = t
            float s = 0.f;
            #pragma unroll
            for (int l = 0; l < 16; ++l) s += M[t * 16 + l];
            float r = 1.f / (s + 1e-6f);
            #pragma unroll
            for (int l = 0; l < 16; ++l) M[t * 16 + l] *= r;
        }
        __syncthreads();
        if (t < 128) {   // col (h,l): h = t>>4, l = t&15
            int h = t >> 4, l = t & 15;
            int base = h * 256 + l;
            float s = 0.f;
            #pragma unroll
            for (int k = 0; k < 16; ++k) s += M[base + k * 16];
            float r = 1.f / (s + 1e-6f);
            #pragma unroll
            for (int k = 0; k < 16; ++k) M[base + k * 16] *= r;
        }
        __syncthreads();
    }

    // zero diagonal
    if (t < 128) { int h = t >> 4, k = t & 15; M[h * 256 + k * 16 + k] = 0.f; }
    __syncthreads();

    // write G_out
    for (int i = t; i < 2048; i += 256) G_out[i] = M[i];

    // Frobenius diversity: V = normalize(rows of G.reshape(H,256))
    // g_reg = 0.02 * (|sum_h v_h|^2 - sum_h |v_h|^2) / 56
    if (t < 128) {
        float s = 0.f;
        #pragma unroll
        for (int l = 0; l < 16; ++l) { float x = M[t * 16 + l]; s += x * x; }
        red[t] = s;
    }
    __syncthreads();
    if (t < 8) {
        float s = 0.f;
        for (int k = 0; k < 16; ++k) s += red[t * 16 + k];
        float n = sqrtf(s);
        float inv = 1.f / fmaxf(n, 1e-8f);
        inv_nrm[t] = inv;
        hsq[t] = s * inv * inv;
    }
    __syncthreads();
    if (t == 0) {
        float tr = 0.f;
        for (int h = 0; h < 8; ++h) tr += hsq[h];
        trace_s = tr;
    }
    __syncthreads();
    // w_j = sum_h V[h,j]; accumulate w_j^2
    float w = 0.f;
    #pragma unroll
    for (int h = 0; h < 8; ++h) w += M[h * 256 + t] * inv_nrm[h];
    red[t] = w * w;
    __syncthreads();
    for (int off = 128; off; off >>= 1) {
        if (t < off) red[t] += red[t + off];
        __syncthreads();
    }
    if (t == 0) g_reg[0] = 0.02f * (red[0] - trace_s) / 56.f;
}

// ---------------------------------------------------------------------------
// Kernel 3: S = softmax(concat(desc,nv) @ W_eff^T + b_eff) over K
// Wave per (b,n) row.  Lane layout: k = lane&15 (output slot), q = lane>>4
// (quarter of the 512-long input).
// ---------------------------------------------------------------------------
__global__ void k_S(const float* __restrict__ desc, const float* __restrict__ nv,
                    const float* __restrict__ W_eff, const float* __restrict__ b_eff,
                    float* __restrict__ S) {
    int row  = blockIdx.x * 4 + (threadIdx.x >> 6);   // 0..8191  (= b*N+n)
    int lane = threadIdx.x & 63;
    int k = lane & 15, q = lane >> 4;
    const float* x = (q < 2) ? (desc + (size_t)row * 256 + q * 128)
                             : (nv   + (size_t)row * 256 + (q - 2) * 128);
    const float* w = W_eff + k * 512 + q * 128;
    const float4* x4 = (const float4*)x;
    const float4* w4 = (const float4*)w;
    float acc = 0.f;
    #pragma unroll
    for (int i = 0; i < 32; ++i) {
        float4 a = x4[i], b = w4[i];
        acc += a.x * b.x + a.y * b.y + a.z * b.z + a.w * b.w;
    }
    acc += __shfl_xor(acc, 16);
    acc += __shfl_xor(acc, 32);
    float logit = acc + b_eff[k];
    float mx = logit;
    #pragma unroll
    for (int off = 8; off; off >>= 1) mx = fmaxf(mx, __shfl_xor(mx, off));
    float e = expf(logit - mx);
    float s = e;
    #pragma unroll
    for (int off = 8; off; off >>= 1) s += __shfl_xor(s, off);
    if (q == 0) S[(size_t)row * 16 + k] = e / s;
}

// ---------------------------------------------------------------------------
// Kernel 4: per-batch regularizer partials (orth sum-of-squares, usage KL)
// ---------------------------------------------------------------------------
__global__ void k_reg(const float* __restrict__ S, float* __restrict__ partials) {
    int b = blockIdx.x, t = threadIdx.x;
    __shared__ float Sl[4096];
    __shared__ float red[256];
    for (int i = t; i < 4096; i += 256) Sl[i] = S[(size_t)b * 4096 + i];
    __syncthreads();
    // StS[k,l] (t -> k = t>>4, l = t&15)
    int k = t >> 4, l = t & 15;
    float s = 0.f;
    for (int n = 0; n < 256; ++n) s += Sl[n * 16 + k] * Sl[n * 16 + l];
    s *= (1.f / 256.f);
    red[t] = (k == l) ? 0.f : s * s;
    __syncthreads();
    for (int off = 128; off; off >>= 1) {
        if (t < off) red[t] += red[t + off];
        __syncthreads();
    }
    if (t == 0) partials[b] = red[0];
    __syncthreads();
    // usage
    if (t < 16) {
        float u = 0.f;
        for (int n = 0; n < 256; ++n) u += Sl[n * 16 + t];
        red[t] = u * (1.f / 256.f);
    }
    __syncthreads();
    if (t == 0) {
        float su = 0.f;
        for (int kk = 0; kk < 16; ++kk) su += red[kk];
        float kl = 0.f;
        for (int kk = 0; kk < 16; ++kk) {
            float un = red[kk] / (su + 1e-8f);
            float uc = fmaxf(un, 1e-8f);
            kl += uc * (logf(uc) - LOG_INV_K);
        }
        partials[32 + b] = kl;
    }
}

// ---------------------------------------------------------------------------
// Kernel 5: main affinity.  One block per (b,h).
//   R = S_b @ G_h   (LDS),  A = R @ S_b^T,  Q = softmax(2A, over m)
//   bias_log = max(x - m - ln(l), ln(1e-8))
// ---------------------------------------------------------------------------
__global__ __launch_bounds__(256) void k_affinity(const float* __restrict__ S,
                                                  const float* __restrict__ G,
                                                  float* __restrict__ bias,
                                                  float* __restrict__ Q) {
    int bh = blockIdx.x;
    int b = bh >> 3, h = bh & 7;
    __shared__ float Sl[4096];     // [n][k] packed
    __shared__ float Rl[4096];     // [n][l] packed
    __shared__ float Gl[256];      // [k][l]
    __shared__ float rmx[256], rln[256], rrc[256];
    int t = threadIdx.x;

    for (int i = t; i < 4096; i += 256) Sl[i] = S[(size_t)b * 4096 + i];
    Gl[t] = G[h * 256 + t];
    __syncthreads();

    float sreg[16], rreg[16];
    #pragma unroll
    for (int k = 0; k < 16; ++k) sreg[k] = Sl[t * 16 + k];
    #pragma unroll
    for (int l = 0; l < 16; ++l) {
        float r = 0.f;
        #pragma unroll
        for (int k = 0; k < 16; ++k) r += sreg[k] * Gl[k * 16 + l];
        rreg[l] = r;
        Rl[t * 16 + l] = r;
    }

    // online softmax over m for row t:  x = 2 * (R[t,:] . S[m,:])
    float mx = -1e30f, lsum = 0.f;
    for (int m = 0; m < 256; ++m) {
        float a = 0.f;
        #pragma unroll
        for (int l = 0; l < 16; ++l) a += rreg[l] * Sl[m * 16 + l];
        float x = 2.f * a;
        float nm = fmaxf(mx, x);
        lsum = lsum * expf(mx - nm) + expf(x - nm);
        mx = nm;
    }
    rmx[t] = mx;
    rln[t] = logf(lsum);
    rrc[t] = 1.f / lsum;
    __syncthreads();

    // epilogue: thread t = column m, loop rows n  -> coalesced writes
    size_t base = (size_t)bh * 65536;
    float* Bp = bias + base;
    float* Qp = Q + base;
    for (int n = 0; n < 256; ++n) {
        float a = 0.f;
        #pragma unroll
        for (int l = 0; l < 16; ++l) a += Rl[n * 16 + l] * sreg[l];
        float x = 2.f * a;
        float e = expf(x - rmx[n]);
        Qp[n * 256 + t] = e * rrc[n];
        Bp[n * 256 + t] = fmaxf(x - rmx[n] - rln[n], LOG_EPS_C);
    }
}

// ---------------------------------------------------------------------------
// Kernel 6: combine scalar regularizers
// ---------------------------------------------------------------------------
__global__ void k_final(const float* __restrict__ partials,
                        const float* __restrict__ g_reg,
                        float* __restrict__ out_reg) {
    if (threadIdx.x == 0) {
        float o = 0.f, kl = 0.f;
        for (int b = 0; b < 32; ++b) { o += partials[b]; kl += partials[32 + b]; }
        float reg_orth  = 0.1f * o / 8192.f;   // mean over B*K*K = 32*256
        float reg_usage = 0.1f * kl / 32.f;
        out_reg[0] = reg_orth + reg_usage + g_reg[0];
    }
}

// ---------------------------------------------------------------------------
extern "C" void kernel_launch(void* const* d_in, const int* in_sizes, int n_in,
                              void* d_out, int out_size, void* d_ws, size_t ws_size,
                              hipStream_t stream) {
    const float* desc     = (const float*)d_in[0];   // [32,256,256]
    const float* nv       = (const float*)d_in[1];   // [32,256,256]
    const float* W_fusion = (const float*)d_in[2];   // [256,512]
    const float* b_fusion = (const float*)d_in[3];   // [256]
    const float* W_slot   = (const float*)d_in[4];   // [16,256]
    const float* b_slot   = (const float*)d_in[5];   // [16]
    const float* G_param  = (const float*)d_in[6];   // [8,16,16]

    float* out = (float*)d_out;
    float* out_bias = out;                       // [32,8,256,256]
    float* out_Q    = out + 16777216;            // [32,8,256,256]
    float* out_reg  = out + 33554432;            // [1]

    float* ws      = (float*)d_ws;
    float* W_eff   = ws;                // 8192
    float* b_eff   = ws + 8192;         // 16
    float* G_out   = ws + 8208;         // 2048
    float* g_reg   = ws + 10256;        // 1 (+15 pad)
    float* S       = ws + 10272;        // 131072
    float* parts   = ws + 141344;       // 64

    k_weff<<<32, 256, 0, stream>>>(W_fusion, b_fusion, W_slot, b_slot, W_eff, b_eff);
    k_G<<<1, 256, 0, stream>>>(G_param, G_out, g_reg);
    k_S<<<2048, 256, 0, stream>>>(desc, nv, W_eff, b_eff, S);
    k_reg<<<32, 256, 0, stream>>>(S, parts);
    k_affinity<<<256, 256, 0, stream>>>(S, G_out, out_bias, out_Q);
    k_final<<<1, 64, 0, stream>>>(parts, g_reg, out_reg);
}

// Round 2
// 250.815 us; speedup vs baseline: 1.2026x; 1.2026x over previous
//
#include <hip/hip_runtime.h>
#include <math.h>

#define LOG_EPS   (-18.420680743952367f)   // ln(1e-8)
#define LOG_INV_K (-2.772588722239781f)    // ln(1/16)

// ---------------------------------------------------------------------------
// Kernel A: blocks 0..31 -> W_eff = W_slot @ W_fusion, b_eff
//           block  32    -> G softmax+sinkhorn+zero-diag + Frobenius reg
//           (writes out_reg[0] = g_reg; reg blocks in kernel C atomicAdd onto it)
// ---------------------------------------------------------------------------
__global__ void kA(const float* __restrict__ W_fusion, const float* __restrict__ b_fusion,
                   const float* __restrict__ W_slot,   const float* __restrict__ b_slot,
                   const float* __restrict__ G_param,
                   float* __restrict__ W_eff, float* __restrict__ b_eff,
                   float* __restrict__ G_out, float* __restrict__ out_reg) {
    int t = threadIdx.x;
    if (blockIdx.x < 32) {
        int idx = blockIdx.x * 256 + t;          // 0..8191
        int k = idx >> 9, j = idx & 511;
        const float* ws = W_slot + k * 256;
        float s = 0.f;
        #pragma unroll 4
        for (int d = 0; d < 256; ++d) s += ws[d] * W_fusion[d * 512 + j];
        W_eff[idx] = s;
        if (idx < 16) {
            float bb = b_slot[idx];
            for (int d = 0; d < 256; ++d) bb += W_slot[idx * 256 + d] * b_fusion[d];
            b_eff[idx] = bb;
        }
        return;
    }
    // ---- G block ----
    __shared__ float M[2048];
    __shared__ float red[256];
    __shared__ float inv_nrm[8];
    __shared__ float hsq[8];
    __shared__ float trace_s;

    if (t < 128) {
        int base = t * 16;
        float v[16]; float mx = -1e30f;
        #pragma unroll
        for (int l = 0; l < 16; ++l) { v[l] = G_param[base + l]; mx = fmaxf(mx, v[l]); }
        float s = 0.f;
        #pragma unroll
        for (int l = 0; l < 16; ++l) { v[l] = expf(v[l] - mx); s += v[l]; }
        float r = 1.f / s;
        #pragma unroll
        for (int l = 0; l < 16; ++l) M[base + l] = fmaxf(v[l] * r, 1e-6f);
    }
    __syncthreads();
    for (int it = 0; it < 10; ++it) {
        if (t < 128) {
            float s = 0.f;
            #pragma unroll
            for (int l = 0; l < 16; ++l) s += M[t * 16 + l];
            float r = 1.f / (s + 1e-6f);
            #pragma unroll
            for (int l = 0; l < 16; ++l) M[t * 16 + l] *= r;
        }
        __syncthreads();
        if (t < 128) {
            int h = t >> 4, l = t & 15, base = h * 256 + l;
            float s = 0.f;
            #pragma unroll
            for (int k = 0; k < 16; ++k) s += M[base + k * 16];
            float r = 1.f / (s + 1e-6f);
            #pragma unroll
            for (int k = 0; k < 16; ++k) M[base + k * 16] *= r;
        }
        __syncthreads();
    }
    if (t < 128) { int h = t >> 4, k = t & 15; M[h * 256 + k * 16 + k] = 0.f; }
    __syncthreads();
    for (int i = t; i < 2048; i += 256) G_out[i] = M[i];

    if (t < 128) {
        float s = 0.f;
        #pragma unroll
        for (int l = 0; l < 16; ++l) { float x = M[t * 16 + l]; s += x * x; }
        red[t] = s;
    }
    __syncthreads();
    if (t < 8) {
        float s = 0.f;
        for (int k = 0; k < 16; ++k) s += red[t * 16 + k];
        float inv = 1.f / fmaxf(sqrtf(s), 1e-8f);
        inv_nrm[t] = inv;
        hsq[t] = s * inv * inv;
    }
    __syncthreads();
    if (t == 0) {
        float tr = 0.f;
        for (int h = 0; h < 8; ++h) tr += hsq[h];
        trace_s = tr;
    }
    __syncthreads();
    float w = 0.f;
    #pragma unroll
    for (int h = 0; h < 8; ++h) w += M[h * 256 + t] * inv_nrm[h];
    red[t] = w * w;
    __syncthreads();
    for (int off = 128; off; off >>= 1) {
        if (t < off) red[t] += red[t + off];
        __syncthreads();
    }
    if (t == 0) out_reg[0] = 0.02f * (red[0] - trace_s) / 56.f;
}

// ---------------------------------------------------------------------------
// Kernel B: S = softmax(concat(desc,nv) @ W_eff^T + b_eff)  (wave per row)
// ---------------------------------------------------------------------------
__global__ void kB(const float* __restrict__ desc, const float* __restrict__ nv,
                   const float* __restrict__ W_eff, const float* __restrict__ b_eff,
                   float* __restrict__ S) {
    int row  = blockIdx.x * 4 + (threadIdx.x >> 6);
    int lane = threadIdx.x & 63;
    int k = lane & 15, q = lane >> 4;
    const float* x = (q < 2) ? (desc + (size_t)row * 256 + q * 128)
                             : (nv   + (size_t)row * 256 + (q - 2) * 128);
    const float4* x4 = (const float4*)x;
    const float4* w4 = (const float4*)(W_eff + k * 512 + q * 128);
    float acc = 0.f;
    #pragma unroll
    for (int i = 0; i < 32; ++i) {
        float4 a = x4[i], b = w4[i];
        acc += a.x * b.x + a.y * b.y + a.z * b.z + a.w * b.w;
    }
    acc += __shfl_xor(acc, 16);
    acc += __shfl_xor(acc, 32);
    float logit = acc + b_eff[k];
    float mx = logit;
    #pragma unroll
    for (int off = 8; off; off >>= 1) mx = fmaxf(mx, __shfl_xor(mx, off));
    float e = __expf(logit - mx);
    float s = e;
    #pragma unroll
    for (int off = 8; off; off >>= 1) s += __shfl_xor(s, off);
    if (q == 0) S[(size_t)row * 16 + k] = e / s;
}

// ---------------------------------------------------------------------------
// Kernel C: blocks 0..1023  -> affinity: blk>>2 = (b,h), blk&3 = 64-row slice
//           blocks 1024..1055 -> per-batch regularizers, atomicAdd into out_reg
// ---------------------------------------------------------------------------
__global__ __launch_bounds__(256) void kC(const float* __restrict__ S,
                                          const float* __restrict__ G,
                                          float* __restrict__ bias,
                                          float* __restrict__ Q,
                                          float* __restrict__ out_reg) {
    __shared__ float Sl[4096];          // S_b  [n][16]
    __shared__ float Gl[256];           // G_h  [k][l]
    __shared__ float Rp[64 * 17];       // R rows (padded, pass-1 lane-strided reads)
    __shared__ float Ru[64 * 16];       // R rows (unpadded, pass-2 b128 broadcast)
    __shared__ float pmax[256], psum[256];
    __shared__ float rmx[64], rln[64], rrc[64];
    int t = threadIdx.x;
    int blk = blockIdx.x;

    if (blk >= 1024) {
        // ---- regularizer block for batch b ----
        int b = blk - 1024;
        for (int i = t; i < 4096; i += 256) Sl[i] = S[(size_t)b * 4096 + i];
        __syncthreads();
        int k = t >> 4, l = t & 15;
        float s = 0.f;
        for (int n = 0; n < 256; ++n) s += Sl[n * 16 + k] * Sl[n * 16 + l];
        s *= (1.f / 256.f);
        pmax[t] = (k == l) ? 0.f : s * s;
        __syncthreads();
        for (int off = 128; off; off >>= 1) {
            if (t < off) pmax[t] += pmax[t + off];
            __syncthreads();
        }
        if (t < 16) {
            float u = 0.f;
            for (int n = 0; n < 256; ++n) u += Sl[n * 16 + t];
            psum[t] = u * (1.f / 256.f);
        }
        __syncthreads();
        if (t == 0) {
            float su = 0.f;
            for (int kk = 0; kk < 16; ++kk) su += psum[kk];
            float kl = 0.f;
            for (int kk = 0; kk < 16; ++kk) {
                float uc = fmaxf(psum[kk] / (su + 1e-8f), 1e-8f);
                kl += uc * (logf(uc) - LOG_INV_K);
            }
            float val = 0.1f * pmax[0] / 8192.f + 0.1f * kl / 32.f;
            atomicAdd(out_reg, val);
        }
        return;
    }

    // ---- affinity ----
    int bh = blk >> 2, qq = blk & 3;
    int b = bh >> 3, h = bh & 7;
    int n0 = qq * 64;

    const float4* Sg = (const float4*)(S + (size_t)b * 4096);
    float4* Sl4 = (float4*)Sl;
    for (int i = t; i < 1024; i += 256) Sl4[i] = Sg[i];
    Gl[t] = G[h * 256 + t];
    __syncthreads();

    // R = S[n0:n0+64] @ G_h
    for (int i = t; i < 1024; i += 256) {
        int r = i >> 4, l = i & 15;
        float s = 0.f;
        #pragma unroll
        for (int k = 0; k < 16; ++k) s += Sl[(n0 + r) * 16 + k] * Gl[k * 16 + l];
        Rp[r * 17 + l] = s;
        Ru[r * 16 + l] = s;
    }
    __syncthreads();

    // pass 1: online softmax, 4-way m-split.  r = t&63, seg = t>>6
    {
        int r = t & 63, seg = t >> 6;
        float rreg[16];
        #pragma unroll
        for (int l = 0; l < 16; ++l) rreg[l] = Rp[r * 17 + l];
        float mx = -1e30f, ls = 0.f;
        const float4* Srow = (const float4*)(Sl + seg * 64 * 16);
        for (int m = 0; m < 64; ++m) {
            float4 s0 = Srow[m * 4 + 0], s1 = Srow[m * 4 + 1];
            float4 s2 = Srow[m * 4 + 2], s3 = Srow[m * 4 + 3];
            float a = rreg[0] * s0.x + rreg[1] * s0.y + rreg[2] * s0.z + rreg[3] * s0.w
                    + rreg[4] * s1.x + rreg[5] * s1.y + rreg[6] * s1.z + rreg[7] * s1.w
                    + rreg[8] * s2.x + rreg[9] * s2.y + rreg[10] * s2.z + rreg[11] * s2.w
                    + rreg[12] * s3.x + rreg[13] * s3.y + rreg[14] * s3.z + rreg[15] * s3.w;
            float x = 2.f * a;
            float nm = fmaxf(mx, x);
            ls = ls * __expf(mx - nm) + __expf(x - nm);
            mx = nm;
        }
        pmax[t] = mx;
        psum[t] = ls;
    }
    __syncthreads();
    if (t < 64) {
        float m0 = pmax[t], m1 = pmax[64 + t], m2 = pmax[128 + t], m3 = pmax[192 + t];
        float M = fmaxf(fmaxf(m0, m1), fmaxf(m2, m3));
        float L = psum[t] * __expf(m0 - M) + psum[64 + t] * __expf(m1 - M)
                + psum[128 + t] * __expf(m2 - M) + psum[192 + t] * __expf(m3 - M);
        rmx[t] = M;
        rln[t] = __logf(L);
        rrc[t] = 1.f / L;
    }
    __syncthreads();

    // pass 2: thread t -> cols 4*(t&63)..+3, rows (t>>6), +4, ... (16 rows)
    {
        int cg = t & 63, rs = t >> 6;
        float sr[4][16];
        #pragma unroll
        for (int j = 0; j < 4; ++j) {
            const float4* p = (const float4*)(Sl + (4 * cg + j) * 16);
            float4 a = p[0], c = p[1], d = p[2], e = p[3];
            sr[j][0]=a.x; sr[j][1]=a.y; sr[j][2]=a.z; sr[j][3]=a.w;
            sr[j][4]=c.x; sr[j][5]=c.y; sr[j][6]=c.z; sr[j][7]=c.w;
            sr[j][8]=d.x; sr[j][9]=d.y; sr[j][10]=d.z; sr[j][11]=d.w;
            sr[j][12]=e.x; sr[j][13]=e.y; sr[j][14]=e.z; sr[j][15]=e.w;
        }
        size_t base = (size_t)bh * 65536;
        for (int rr = rs; rr < 64; rr += 4) {
            int n = n0 + rr;
            const float4* rp = (const float4*)(Ru + rr * 16);
            float4 r0 = rp[0], r1 = rp[1], r2 = rp[2], r3 = rp[3];
            float rv[16] = { r0.x,r0.y,r0.z,r0.w, r1.x,r1.y,r1.z,r1.w,
                             r2.x,r2.y,r2.z,r2.w, r3.x,r3.y,r3.z,r3.w };
            float m_ = rmx[rr], lnl = rln[rr], rc = rrc[rr];
            float4 qv, bv;
            float* qp = (float*)&qv;
            float* bp = (float*)&bv;
            #pragma unroll
            for (int j = 0; j < 4; ++j) {
                float a = 0.f;
                #pragma unroll
                for (int l = 0; l < 16; ++l) a += rv[l] * sr[j][l];
                float xm = 2.f * a - m_;
                qp[j] = __expf(xm) * rc;
                bp[j] = fmaxf(xm - lnl, LOG_EPS);
            }
            *(float4*)(Q    + base + (size_t)n * 256 + 4 * cg) = qv;
            *(float4*)(bias + base + (size_t)n * 256 + 4 * cg) = bv;
        }
    }
}

// ---------------------------------------------------------------------------
extern "C" void kernel_launch(void* const* d_in, const int* in_sizes, int n_in,
                              void* d_out, int out_size, void* d_ws, size_t ws_size,
                              hipStream_t stream) {
    const float* desc     = (const float*)d_in[0];
    const float* nv       = (const float*)d_in[1];
    const float* W_fusion = (const float*)d_in[2];
    const float* b_fusion = (const float*)d_in[3];
    const float* W_slot   = (const float*)d_in[4];
    const float* b_slot   = (const float*)d_in[5];
    const float* G_param  = (const float*)d_in[6];

    float* out = (float*)d_out;
    float* out_bias = out;
    float* out_Q    = out + 16777216;
    float* out_reg  = out + 33554432;

    float* ws    = (float*)d_ws;
    float* W_eff = ws;           // 8192
    float* b_eff = ws + 8192;    // 16
    float* G_out = ws + 8208;    // 2048
    float* S     = ws + 10256;   // 131072

    kA<<<33, 256, 0, stream>>>(W_fusion, b_fusion, W_slot, b_slot, G_param,
                               W_eff, b_eff, G_out, out_reg);
    kB<<<2048, 256, 0, stream>>>(desc, nv, W_eff, b_eff, S);
    kC<<<1056, 256, 0, stream>>>(S, G_out, out_bias, out_Q, out_reg);
}